// Round 9
// baseline (4273.573 us; speedup 1.0000x reference)
//
#include <hip/hip_runtime.h>
#include <cmath>

#define D3   192
#define SZP  (D3*D3)        // 36864, z stride
#define NVOX (D3*D3*D3)     // 7077888
#define NTOT (2*NVOX)       // 14155776
#define NBLK (NTOT/256)     // 55296
#define W3   (NTOT/64)      // 221184 packed words total
#define WGRP (W3/256)       // 864 word-groups (256 words each)
#define NSUM (W3/64)        // 3456 summary words
#define NQ   (NTOT/4)       // quads
#define NQB  (NQ/256)
#define BPB  (NVOX/256)     // 27648 blocks per volume

// hysteresis multi-step tile
#define HT 16
#define HH 8
#define HL (HT+2*HH)        // 32
#define HLDS (HL*HL*3)      // 3072 u64 (24 KB per buffer)
#define NHT  (12*12*2)      // 288 tiles

#define GBLK 256            // cooperative grid: 256 blocks x 256 threads
#define TT   (GBLK*256)     // 65536 threads

typedef unsigned long long u64;

struct Taps13 { float k[13]; };

__device__ __forceinline__ void coords(int idx, int& x, int& y, int& z, int& b) {
  x = idx % D3;
  y = (idx / D3) % D3;
  z = (idx / SZP) % D3;
  b = idx / NVOX;
}

// ---------------- frontend (unchanged from R8) ----------------
template<int AXIS, int R>
__global__ void __launch_bounds__(256) conv1d_k(const float* __restrict__ in,
                                                float* __restrict__ out, Taps13 t) {
  int idx = blockIdx.x * 256 + threadIdx.x;
  int x, y, z, b; coords(idx, x, y, z, b);
  int c = (AXIS == 0) ? z : (AXIS == 1) ? y : x;
  const int stride = (AXIS == 0) ? SZP : (AXIS == 1) ? D3 : 1;
  float acc = 0.f;
#pragma unroll
  for (int i = -R; i <= R; ++i) {
    int cc = c + i;
    if (cc >= 0 && cc < D3)
      acc = __fadd_rn(acc, __fmul_rn(t.k[i + R], in[idx + i * stride]));
  }
  out[idx] = acc;
}

__global__ void __launch_bounds__(256) surf_k(const float* __restrict__ s,
                                              float* __restrict__ surf,
                                              float* __restrict__ bmax,
                                              float scale) {
  int idx = blockIdx.x * 256 + threadIdx.x;
  int x, y, z, b; coords(idx, x, y, z, b);
  float ctr = s[idx];
  float fxx, fyy, fzz;
  { float acc = 0.f;
    if (z > 0)      acc = __fadd_rn(acc, __fmul_rn(1.f, s[idx - SZP]));
    acc = __fadd_rn(acc, __fmul_rn(-2.f, ctr));
    if (z < D3 - 1) acc = __fadd_rn(acc, __fmul_rn(1.f, s[idx + SZP]));
    fxx = __fmul_rn(acc, scale); }
  { float acc = 0.f;
    if (y > 0)      acc = __fadd_rn(acc, __fmul_rn(1.f, s[idx - D3]));
    acc = __fadd_rn(acc, __fmul_rn(-2.f, ctr));
    if (y < D3 - 1) acc = __fadd_rn(acc, __fmul_rn(1.f, s[idx + D3]));
    fyy = __fmul_rn(acc, scale); }
  { float acc = 0.f;
    if (x > 0)      acc = __fadd_rn(acc, __fmul_rn(1.f, s[idx - 1]));
    acc = __fadd_rn(acc, __fmul_rn(-2.f, ctr));
    if (x < D3 - 1) acc = __fadd_rn(acc, __fmul_rn(1.f, s[idx + 1]));
    fzz = __fmul_rn(acc, scale); }

  float num = __fadd_rn(__fmul_rn(fxx, fxx), __fmul_rn(fyy, fyy));
  float den = __fmul_rn(0.25f, __fadd_rn(__fmul_rn(fzz, fzz), 1e-7f));
  float arg = __fdiv_rn(-num, den);
  float sv  = __fmul_rn(expf(arg), fabsf(fzz));
  surf[idx] = sv;

  float m = sv;
  #pragma unroll
  for (int off = 32; off > 0; off >>= 1) m = fmaxf(m, __shfl_down(m, off));
  __shared__ float wred[4];
  int lane = threadIdx.x & 63, wid = threadIdx.x >> 6;
  if (lane == 0) wred[wid] = m;
  __syncthreads();
  if (threadIdx.x == 0)
    bmax[blockIdx.x] = fmaxf(fmaxf(wred[0], wred[1]), fmaxf(wred[2], wred[3]));
}

__global__ void __launch_bounds__(256) reduce_max_k(const float* __restrict__ bmax,
                                                    unsigned int* __restrict__ mxp) {
  int b = blockIdx.x;
  const float* p = bmax + b * BPB;
  float m = 0.f;
  for (int i = threadIdx.x; i < BPB; i += 256) m = fmaxf(m, p[i]);
  #pragma unroll
  for (int off = 32; off > 0; off >>= 1) m = fmaxf(m, __shfl_down(m, off));
  __shared__ float wred[4];
  int lane = threadIdx.x & 63, wid = threadIdx.x >> 6;
  if (lane == 0) wred[wid] = m;
  __syncthreads();
  if (threadIdx.x == 0)
    mxp[b] = __float_as_uint(fmaxf(fmaxf(wred[0], wred[1]), fmaxf(wred[2], wred[3])));
}

__global__ void __launch_bounds__(256) mask_init_pack_k(const float* __restrict__ v,
                                                        const float* __restrict__ s1,
                                                        const float* __restrict__ s2,
                                                        const unsigned int* __restrict__ mx,
                                                        u64* __restrict__ lowW,
                                                        u64* __restrict__ mW) {
  int idx = blockIdx.x * 256 + threadIdx.x;
  int b = idx / NVOX;
  float m1 = __uint_as_float(mx[b]);
  float m2 = __uint_as_float(mx[2 + b]);
  float n1 = (m1 > 0.f) ? __fdiv_rn(s1[idx], __fadd_rn(m1, 1e-7f)) : 0.f;
  float n2 = (m2 > 0.f) ? __fdiv_rn(s2[idx], __fadd_rn(m2, 1e-7f)) : 0.f;
  float vol = __fmul_rn(v[idx], fmaxf(n1, n2));
  u64 bl = __ballot(vol > 0.5f);
  u64 bh = __ballot(vol > 0.9f);
  if ((threadIdx.x & 63) == 0) {
    lowW[idx >> 6] = bl;
    mW[idx >> 6]   = bh;
  }
}

// ---------------- cooperative pipeline ----------------
struct Flag { int v; int pad[15]; };   // 64B padded -> contention-free arrival

struct PipeArgs {
  const u64* lowW; u64* mWA; u64* mWB;
  int* labA; int* labB;
  u64* chgWA; u64* chgWB; u64* sumA; u64* sumB;
  int* chgH; int* chgC; int* hF0; int* hF1;
  Flag* arr; int* go;
  float* outp;
};

__device__ __forceinline__ int imax2(int a, int b) { return a > b ? a : b; }

// grid barrier: padded arrival flags + single release word. ~O(1 L2 roundtrip).
__device__ __forceinline__ void gbar(Flag* arr, int* go, int rnd) {
  __syncthreads();
  if (threadIdx.x == 0) {
    __threadfence();
    __hip_atomic_store(&arr[blockIdx.x].v, rnd, __ATOMIC_RELEASE, __HIP_MEMORY_SCOPE_AGENT);
  }
  if (blockIdx.x == 0) {
    // 256 threads each own exactly one flag (grid == blockDim)
    while (__hip_atomic_load(&arr[threadIdx.x].v, __ATOMIC_ACQUIRE,
                             __HIP_MEMORY_SCOPE_AGENT) < rnd)
      __builtin_amdgcn_s_sleep(1);
    __syncthreads();
    if (threadIdx.x == 0) {
      __threadfence();
      __hip_atomic_store(go, rnd, __ATOMIC_RELEASE, __HIP_MEMORY_SCOPE_AGENT);
    }
  } else if (threadIdx.x == 0) {
    while (__hip_atomic_load(go, __ATOMIC_ACQUIRE, __HIP_MEMORY_SCOPE_AGENT) < rnd)
      __builtin_amdgcn_s_sleep(1);
  }
  __syncthreads();
}

__global__ void __launch_bounds__(256, 1) pipeline_k(PipeArgs a) {
  __shared__ u64 sA[HLDS], sB[HLDS];
  __shared__ int blkC;
  const int t = threadIdx.x;
  const int gtid = blockIdx.x * 256 + t;
  int rnd = 0;

  // ================= Phase H: hysteresis, up to 32 x (8 exact steps) ==========
  u64* hsrc = a.mWA; u64* hdst = a.mWB;
  int* fp = a.hF1;   int* fc = a.hF0;
  for (int it = 0; it < 32; ++it) {
    for (int vt = blockIdx.x; vt < NHT; vt += GBLK) {
      int tyi = vt % 12, tzi = (vt / 12) % 12, tb = vt / 144;
      bool act = true;
      if (it > 0) {
        act = false;
        for (int dz = -1; dz <= 1 && !act; ++dz) {
          int zz = tzi + dz; if (zz < 0 || zz >= 12) continue;
          for (int dy = -1; dy <= 1; ++dy) {
            int yy = tyi + dy; if (yy < 0 || yy >= 12) continue;
            if (fp[yy + 12 * zz + 144 * tb]) { act = true; break; }
          }
        }
      }
      if (!act) { if (t == 0) fc[vt] = 0; continue; }

      if (t == 0) blkC = 0;
      __syncthreads();                      // protects sA/sB + blkC across tiles
      const int y0 = tyi * HT - HH;
      const int z0 = tzi * HT - HH;

      u64 lowr[4][3], orig[4][3];
#pragma unroll
      for (int j = 0; j < 4; ++j) {
        int l = t + 256 * j;
        int yy = l & 31, zz = l >> 5;
        int y = y0 + yy, z = z0 + zz;
        bool in = (y >= 0 && y < D3 && z >= 0 && z < D3);
        int wb = 3 * y + 576 * z + 110592 * tb;
#pragma unroll
        for (int xw = 0; xw < 3; ++xw) {
          u64 sv = in ? hsrc[wb + xw]   : 0ull;
          u64 lv = in ? a.lowW[wb + xw] : 0ull;
          sA[l * 3 + xw] = sv;
          orig[j][xw] = sv;
          lowr[j][xw] = lv;
        }
      }
      __syncthreads();

      u64* cur = sA; u64* nxt = sB;
      for (int s = 0; s < 8; ++s) {
#pragma unroll
        for (int j = 0; j < 4; ++j) {
          int l = t + 256 * j;
          int yy = l & 31, zz = l >> 5;
          int base = l * 3;
          u64 w0 = cur[base], w1 = cur[base + 1], w2 = cur[base + 2];
          u64 n0 = w0 | (w0 << 1) | (w0 >> 1) | (w1 << 63);
          u64 n1 = w1 | (w1 << 1) | (w1 >> 1) | (w0 >> 63) | (w2 << 63);
          u64 n2 = w2 | (w2 << 1) | (w2 >> 1) | (w1 >> 63);
          if (yy > 0)  { n0 |= cur[base - 3];  n1 |= cur[base - 2];  n2 |= cur[base - 1]; }
          if (yy < 31) { n0 |= cur[base + 3];  n1 |= cur[base + 4];  n2 |= cur[base + 5]; }
          if (zz > 0)  { n0 |= cur[base - 96]; n1 |= cur[base - 95]; n2 |= cur[base - 94]; }
          if (zz < 31) { n0 |= cur[base + 96]; n1 |= cur[base + 97]; n2 |= cur[base + 98]; }
          nxt[base]     = n0 & lowr[j][0];
          nxt[base + 1] = n1 & lowr[j][1];
          nxt[base + 2] = n2 & lowr[j][2];
        }
        __syncthreads();
        u64* tmp = cur; cur = nxt; nxt = tmp;
      }

      bool ch = false;
#pragma unroll
      for (int j = 0; j < 4; ++j) {
        int l = t + 256 * j;
        int yy = l & 31, zz = l >> 5;
        if (yy >= HH && yy < HH + HT && zz >= HH && zz < HH + HT) {
          int y = y0 + yy, z = z0 + zz;
          int wb = 3 * y + 576 * z + 110592 * tb;
#pragma unroll
          for (int xw = 0; xw < 3; ++xw) {
            u64 o = cur[l * 3 + xw];
            ch |= (o != orig[j][xw]);
            hdst[wb + xw] = o;
          }
        }
      }
      if (ch) blkC = 1;
      __syncthreads();
      if (t == 0) {
        fc[vt] = blkC;
        if (blkC) __hip_atomic_store(&a.chgH[it], 1, __ATOMIC_RELAXED, __HIP_MEMORY_SCOPE_AGENT);
      }
    }
    gbar(a.arr, a.go, ++rnd);
    { u64* tm = hsrc; hsrc = hdst; hdst = tm; }
    { int* ti = fp; fp = fc; fc = ti; }
    if (a.chgH[it] == 0) break;            // uniform: converged
  }
  // final hysteresis state in hsrc

  // ============ Phase B: z-closing fused label-init (writes labA) =============
  for (int q = gtid; q < NQ; q += TT) {
    int idx = q << 2;
    int w = idx >> 6, sh = idx & 63;
    int z = (w / 576) % D3;
    u64 c   = hsrc[w];
    u64 zm1 = (z > 0)      ? hsrc[w - 576]  : 0ull;
    u64 zm2 = (z > 1)      ? hsrc[w - 1152] : 0ull;
    u64 zp1 = (z < D3 - 1) ? hsrc[w + 576]  : 0ull;
    u64 zp2 = (z < D3 - 2) ? hsrc[w + 1152] : 0ull;
    u64 e = c | zm1 | zp1;
    if (z > 0)      e &= (zm2 | zm1 | c);
    if (z < D3 - 1) e &= (c | zp1 | zp2);
    unsigned bits = (unsigned)((e >> sh) & 0xFull);
    int rel = idx % NVOX;
    int4 L;
    L.x = (bits & 1u) ? rel + 1 : 0;
    L.y = (bits & 2u) ? rel + 2 : 0;
    L.z = (bits & 4u) ? rel + 3 : 0;
    L.w = (bits & 8u) ? rel + 4 : 0;
    *(int4*)(a.labA + idx) = L;
  }
  gbar(a.arr, a.go, ++rnd);

  // ====== Phase C: CC, up to 256 exact Jacobi steps, voxel skip + summary =====
  int* cs = a.labA; int* cd = a.labB;
  u64* cp = a.chgWA; u64* cn = a.chgWB;
  u64* sp = a.sumA;  u64* sn = a.sumB;
  for (int it = 0; it < 256; ++it) {
    for (int vb = blockIdx.x; vb < WGRP; vb += GBLK) {
      const int w = vb * 256 + t;
      const int xw = w % 3;
      const int y  = (w / 3) % D3;
      const int z  = (w / 576) % D3;

      u64 F, U;
      if (it == 0) {
        F = ~0ull; U = 0ull;
      } else {
        u64 c  = ((sp[w >> 6] >> (w & 63)) & 1ull) ? cp[w] : 0ull;
        u64 cl = 0ull, cr = 0ull, ym = 0ull, yp = 0ull, zm = 0ull, zp = 0ull;
        if (xw > 0      && ((sp[(w - 1) >> 6]   >> ((w - 1) & 63))   & 1ull)) cl = cp[w - 1];
        if (xw < 2      && ((sp[(w + 1) >> 6]   >> ((w + 1) & 63))   & 1ull)) cr = cp[w + 1];
        if (y > 0       && ((sp[(w - 3) >> 6]   >> ((w - 3) & 63))   & 1ull)) ym = cp[w - 3];
        if (y < D3 - 1  && ((sp[(w + 3) >> 6]   >> ((w + 3) & 63))   & 1ull)) yp = cp[w + 3];
        if (z > 0       && ((sp[(w - 576) >> 6] >> ((w - 576) & 63)) & 1ull)) zm = cp[w - 576];
        if (z < D3 - 1  && ((sp[(w + 576) >> 6] >> ((w + 576) & 63)) & 1ull)) zp = cp[w + 576];
        u64 nb = (c << 1) | (c >> 1) | (cl >> 63) | (cr << 63) | ym | yp | zm | zp;
        if ((nb | c) == 0ull) { F = 0ull; U = 0ull; }
        else {
          // closed-mask == (labels>0 in cs at these voxels); use label test per quad
          F = nb; U = c & ~nb;   // mask applied inside via s>0 tests (lab==0 stays 0)
        }
      }

      u64 P = F | U;
      u64 newc = 0;
      if (P) {
        int idx0 = xw * 64 + D3 * y + SZP * z + (w / 110592) * NVOX;
#pragma unroll
        for (int q = 0; q < 16; ++q) {
          if (!((P >> (4 * q)) & 0xFull)) continue;
          int idx = idx0 + 4 * q;
          int4 s = *(const int4*)(cs + idx);
          int4 o = s;
          if ((F >> (4 * q)) & 0xFull) {
            int x = xw * 64 + 4 * q;
            const int4 z4 = make_int4(0, 0, 0, 0);
            int4 yv = (y > 0)      ? *(const int4*)(cs + idx - D3)  : z4;
            int4 yw = (y < D3 - 1) ? *(const int4*)(cs + idx + D3)  : z4;
            int4 zv = (z > 0)      ? *(const int4*)(cs + idx - SZP) : z4;
            int4 zw = (z < D3 - 1) ? *(const int4*)(cs + idx + SZP) : z4;
            int lf = (x > 0)       ? cs[idx - 1] : 0;
            int rt = (x < D3 - 4)  ? cs[idx + 4] : 0;
            o.x = s.x ? imax2(imax2(imax2(s.x, lf),  imax2(s.y, yv.x)), imax2(imax2(yw.x, zv.x), zw.x)) : 0;
            o.y = s.y ? imax2(imax2(imax2(s.y, s.x), imax2(s.z, yv.y)), imax2(imax2(yw.y, zv.y), zw.y)) : 0;
            o.z = s.z ? imax2(imax2(imax2(s.z, s.y), imax2(s.w, yv.z)), imax2(imax2(yw.z, zv.z), zw.z)) : 0;
            o.w = s.w ? imax2(imax2(imax2(s.w, s.z), imax2(rt,  yv.w)), imax2(imax2(yw.w, zv.w), zw.w)) : 0;
          }
          *(int4*)(cd + idx) = o;
          u64 df = (u64)((o.x != s.x) | ((o.y != s.y) << 1) |
                         ((o.z != s.z) << 2) | ((o.w != s.w) << 3));
          newc |= df << (4 * q);
        }
      }

      u64 bal = __ballot(newc != 0ull);
      if (newc) cn[w] = newc;
      if ((t & 63) == 0) {
        sn[w >> 6] = bal;
        if (bal) __hip_atomic_store(&a.chgC[it], 1, __ATOMIC_RELAXED, __HIP_MEMORY_SCOPE_AGENT);
      }
    }
    gbar(a.arr, a.go, ++rnd);
    { int* ti = cs; cs = cd; cd = ti; }
    { u64* tm = cp; cp = cn; cn = tm; }
    { u64* tm = sp; sp = sn; sn = tm; }
    if (a.chgC[it] == 0) break;            // uniform: converged
  }
  // final labels in cs (skipped voxels equal in both buffers)

  // ============ Phase P: ensure labels land in labA ===========================
  if (cs != a.labA) {
    for (int q = gtid; q < NQ; q += TT)
      *(int4*)(a.labA + (q << 2)) = *(const int4*)(cs + (q << 2));
    gbar(a.arr, a.go, ++rnd);
  }

  // ============ Phase Z: zero counts (labB region) ============================
  unsigned int* counts = (unsigned int*)a.labB;
  for (int q = gtid; q < NQ; q += TT)
    *(int4*)((int*)counts + (q << 2)) = make_int4(0, 0, 0, 0);
  gbar(a.arr, a.go, ++rnd);

  // ============ Phase CT: component sizes =====================================
  for (int q = gtid; q < NQ; q += TT) {
    int idx = q << 2;
    int b = idx / NVOX;
    int4 L = *(const int4*)(a.labA + idx);
    unsigned int* cb = counts + (size_t)b * NVOX;
    if (L.x > 0) atomicAdd(&cb[L.x - 1], 1u);
    if (L.y > 0) atomicAdd(&cb[L.y - 1], 1u);
    if (L.z > 0) atomicAdd(&cb[L.z - 1], 1u);
    if (L.w > 0) atomicAdd(&cb[L.w - 1], 1u);
  }
  gbar(a.arr, a.go, ++rnd);

  // ============ Phase F: dust filter -> output ================================
  for (int q = gtid; q < NQ; q += TT) {
    int idx = q << 2;
    int b = idx / NVOX;
    int4 L = *(const int4*)(a.labA + idx);   // labA aliases out: read before write
    const unsigned int* cb = counts + (size_t)b * NVOX;
    float4 rr;
    rr.x = (L.x > 0 && cb[L.x - 1] >= 100u) ? 1.f : 0.f;
    rr.y = (L.y > 0 && cb[L.y - 1] >= 100u) ? 1.f : 0.f;
    rr.z = (L.z > 0 && cb[L.z - 1] >= 100u) ? 1.f : 0.f;
    rr.w = (L.w > 0 && cb[L.w - 1] >= 100u) ? 1.f : 0.f;
    *(float4*)(a.outp + idx) = rr;
  }
}

// ---- host-side: emulate numpy f32 pairwise sum exactly ----
static float np_sum_f32(const float* a, int n) {
  if (n < 8) { float res = 0.f; for (int i = 0; i < n; i++) res += a[i]; return res; }
  float r[8]; for (int j = 0; j < 8; j++) r[j] = a[j];
  int i = 8;
  for (; i < n - (n % 8); i += 8) for (int j = 0; j < 8; j++) r[j] += a[i + j];
  float res = ((r[0] + r[1]) + (r[2] + r[3])) + ((r[4] + r[5]) + (r[6] + r[7]));
  for (; i < n; i++) res += a[i];
  return res;
}

extern "C" void kernel_launch(void* const* d_in, const int* in_sizes, int n_in,
                              void* d_out, int out_size, void* d_ws, size_t ws_size,
                              hipStream_t stream) {
  const float* v = (const float*)d_in[0];
  float* out = (float*)d_out;
  char* base = (char*)d_ws;
  const size_t SZBUF = (size_t)NTOT * 4;
  const size_t SZW   = (size_t)W3 * 8;     // 1.77 MB per packed mask

  float* A  = (float*)base;
  float* Cf = (float*)(base + SZBUF);
  unsigned int* mx = (unsigned int*)(base + 2 * SZBUF);
  float* bmax = (float*)(base + 2 * SZBUF + 256);
  float* Bf = (float*)d_out;

  u64* lowW  = (u64*)base;
  u64* mWA   = (u64*)(base + SZW);
  u64* mWB   = (u64*)(base + 2 * SZW);
  u64* chgWA = (u64*)(base + 3 * SZW);
  u64* chgWB = (u64*)(base + 4 * SZW);
  u64* sumA  = (u64*)(base + 5 * SZW);     // NSUM u64
  u64* sumB  = sumA + NSUM;
  int* chgH  = (int*)(sumB + NSUM);        // 32
  int* chgC  = chgH + 32;                  // 256
  int* hF0   = chgC + 256;                 // 288
  int* hF1   = hF0 + NHT;                  // 288
  // align barrier flags to 64B (offset arithmetic: all prior counts are multiples of 4B;
  // chgH starts 64B-aligned, 864 ints = 3456B -> still 64B-aligned)
  Flag* arr  = (Flag*)(hF1 + NHT);
  int* go    = (int*)(arr + GBLK);
  size_t ctrlBytes = (char*)(go + 16) - (char*)chgH;

  int* labA = (int*)Bf;
  int* labB = (int*)Cf;

  dim3 g(NBLK), blk(256);

  const double sigmas[2] = {1.0, 2.0};
  for (int si = 0; si < 2; ++si) {
    double sigma = sigmas[si];
    int r = (int)(3.0 * sigma + 0.5);
    int n = 2 * r + 1;
    float a[13], k[13];
    for (int i = 0; i < n; i++) {
      float xx = (float)(i - r);
      float t  = xx * xx;
      float arg = -(t) / (float)(2.0 * sigma * sigma);
      a[i] = (float)std::exp((double)arg);
    }
    float ssum = np_sum_f32(a, n);
    for (int i = 0; i < n; i++) k[i] = a[i] / ssum;

    Taps13 T = {};
    for (int i = 0; i < n; i++) T.k[i] = k[i];
    float scale = (float)(sigma * sigma);
    float* starget = (si == 0) ? Cf : Bf;

    if (r == 3) {
      conv1d_k<0, 3><<<g, blk, 0, stream>>>(v,  A,  T);
      conv1d_k<1, 3><<<g, blk, 0, stream>>>(A,  Bf, T);
      conv1d_k<2, 3><<<g, blk, 0, stream>>>(Bf, A,  T);
    } else {
      conv1d_k<0, 6><<<g, blk, 0, stream>>>(v,  A,  T);
      conv1d_k<1, 6><<<g, blk, 0, stream>>>(A,  Bf, T);
      conv1d_k<2, 6><<<g, blk, 0, stream>>>(Bf, A,  T);
    }
    surf_k<<<g, blk, 0, stream>>>(A, starget, bmax, scale);
    reduce_max_k<<<dim3(2), blk, 0, stream>>>(bmax, mx + 2 * si);
  }

  // reset all control state every call (replays must be deterministic)
  hipMemsetAsync(chgH, 0, ctrlBytes, stream);
  mask_init_pack_k<<<g, blk, 0, stream>>>(v, Cf, Bf, mx, lowW, mWA);

  PipeArgs pa{lowW, mWA, mWB, labA, labB, chgWA, chgWB, sumA, sumB,
              chgH, chgC, hF0, hF1, arr, go, out};
  void* args[] = {&pa};
  hipLaunchCooperativeKernel((const void*)pipeline_k, dim3(GBLK), dim3(256),
                             args, 0, stream);
}

// Round 10
// 2474.387 us; speedup vs baseline: 1.7271x; 1.7271x over previous
//
#include <hip/hip_runtime.h>
#include <cmath>

#define D3   192
#define SZP  (D3*D3)        // 36864, z stride
#define NVOX (D3*D3*D3)     // 7077888
#define NTOT (2*NVOX)       // 14155776
#define NBLK (NTOT/256)     // 55296
#define W3   (NTOT/64)      // 221184 packed words total
#define WBLK (W3/256)       // 864
#define NSUM (W3/64)        // 3456 summary words
#define NQ   (NTOT/4)       // quads
#define NQB  (NQ/256)       // 13824
#define BPB  (NVOX/256)     // 27648 blocks per volume

// hysteresis multi-step tile
#define HT 16
#define HH 8
#define HL (HT+2*HH)        // 32
#define HLDS (HL*HL*3)      // 3072 u64 (24 KB per buffer)
#define NHT  (12*12*2)      // 288 tiles

// CC multi-step tile (R7-proven): interior 32x8x8, halo 4 -> 4 steps/dispatch
#define CRX 40
#define CRY 16
#define CRZ 16
#define CRN (CRX*CRY*CRZ)   // 10240 cells
#define CJ  (CRN/256)       // 40 cells/thread
#define NCT (6*24*24*2)     // 6912 cc regions

typedef unsigned long long u64;

struct Taps13 { float k[13]; };

__device__ __forceinline__ void coords(int idx, int& x, int& y, int& z, int& b) {
  x = idx % D3;
  y = (idx / D3) % D3;
  z = (idx / SZP) % D3;
  b = idx / NVOX;
}

// 1D 'same' zero-padded correlation along AXIS; accumulation order i=-R..R
// with separate rn mul/add to match XLA's un-contracted  out = out + k[i]*v.
template<int AXIS, int R>
__global__ void __launch_bounds__(256) conv1d_k(const float* __restrict__ in,
                                                float* __restrict__ out, Taps13 t) {
  int idx = blockIdx.x * 256 + threadIdx.x;
  int x, y, z, b; coords(idx, x, y, z, b);
  int c = (AXIS == 0) ? z : (AXIS == 1) ? y : x;
  const int stride = (AXIS == 0) ? SZP : (AXIS == 1) ? D3 : 1;
  float acc = 0.f;
#pragma unroll
  for (int i = -R; i <= R; ++i) {
    int cc = c + i;
    if (cc >= 0 && cc < D3)
      acc = __fadd_rn(acc, __fmul_rn(t.k[i + R], in[idx + i * stride]));
  }
  out[idx] = acc;
}

// fused fxx/fyy/fzz + surfaceness; per-BLOCK max to bmax (plain store)
__global__ void __launch_bounds__(256) surf_k(const float* __restrict__ s,
                                              float* __restrict__ surf,
                                              float* __restrict__ bmax,
                                              float scale) {
  int idx = blockIdx.x * 256 + threadIdx.x;
  int x, y, z, b; coords(idx, x, y, z, b);
  float ctr = s[idx];
  float fxx, fyy, fzz;
  { float acc = 0.f;
    if (z > 0)      acc = __fadd_rn(acc, __fmul_rn(1.f, s[idx - SZP]));
    acc = __fadd_rn(acc, __fmul_rn(-2.f, ctr));
    if (z < D3 - 1) acc = __fadd_rn(acc, __fmul_rn(1.f, s[idx + SZP]));
    fxx = __fmul_rn(acc, scale); }
  { float acc = 0.f;
    if (y > 0)      acc = __fadd_rn(acc, __fmul_rn(1.f, s[idx - D3]));
    acc = __fadd_rn(acc, __fmul_rn(-2.f, ctr));
    if (y < D3 - 1) acc = __fadd_rn(acc, __fmul_rn(1.f, s[idx + D3]));
    fyy = __fmul_rn(acc, scale); }
  { float acc = 0.f;
    if (x > 0)      acc = __fadd_rn(acc, __fmul_rn(1.f, s[idx - 1]));
    acc = __fadd_rn(acc, __fmul_rn(-2.f, ctr));
    if (x < D3 - 1) acc = __fadd_rn(acc, __fmul_rn(1.f, s[idx + 1]));
    fzz = __fmul_rn(acc, scale); }

  float num = __fadd_rn(__fmul_rn(fxx, fxx), __fmul_rn(fyy, fyy));
  float den = __fmul_rn(0.25f, __fadd_rn(__fmul_rn(fzz, fzz), 1e-7f));
  float arg = __fdiv_rn(-num, den);
  float sv  = __fmul_rn(expf(arg), fabsf(fzz));
  surf[idx] = sv;

  float m = sv;
  #pragma unroll
  for (int off = 32; off > 0; off >>= 1) m = fmaxf(m, __shfl_down(m, off));
  __shared__ float wred[4];
  int lane = threadIdx.x & 63, wid = threadIdx.x >> 6;
  if (lane == 0) wred[wid] = m;
  __syncthreads();
  if (threadIdx.x == 0)
    bmax[blockIdx.x] = fmaxf(fmaxf(wred[0], wred[1]), fmaxf(wred[2], wred[3]));
}

__global__ void __launch_bounds__(256) reduce_max_k(const float* __restrict__ bmax,
                                                    unsigned int* __restrict__ mxp) {
  int b = blockIdx.x;
  const float* p = bmax + b * BPB;
  float m = 0.f;
  for (int i = threadIdx.x; i < BPB; i += 256) m = fmaxf(m, p[i]);
  #pragma unroll
  for (int off = 32; off > 0; off >>= 1) m = fmaxf(m, __shfl_down(m, off));
  __shared__ float wred[4];
  int lane = threadIdx.x & 63, wid = threadIdx.x >> 6;
  if (lane == 0) wred[wid] = m;
  __syncthreads();
  if (threadIdx.x == 0)
    mxp[b] = __float_as_uint(fmaxf(fmaxf(wred[0], wred[1]), fmaxf(wred[2], wred[3])));
}

__global__ void __launch_bounds__(256) mask_init_pack_k(const float* __restrict__ v,
                                                        const float* __restrict__ s1,
                                                        const float* __restrict__ s2,
                                                        const unsigned int* __restrict__ mx,
                                                        u64* __restrict__ lowW,
                                                        u64* __restrict__ mW) {
  int idx = blockIdx.x * 256 + threadIdx.x;
  int b = idx / NVOX;
  float m1 = __uint_as_float(mx[b]);
  float m2 = __uint_as_float(mx[2 + b]);
  float n1 = (m1 > 0.f) ? __fdiv_rn(s1[idx], __fadd_rn(m1, 1e-7f)) : 0.f;
  float n2 = (m2 > 0.f) ? __fdiv_rn(s2[idx], __fadd_rn(m2, 1e-7f)) : 0.f;
  float vol = __fmul_rn(v[idx], fmaxf(n1, n2));
  u64 bl = __ballot(vol > 0.5f);
  u64 bh = __ballot(vol > 0.9f);
  if ((threadIdx.x & 63) == 0) {
    lowW[idx >> 6] = bl;
    mW[idx >> 6]   = bh;
  }
}

// 8 exact flood-fill steps per dispatch (halo-8 LDS tile), tile-level 9-hood skip
__global__ void __launch_bounds__(256) hyst8_k(const u64* __restrict__ src,
                                               u64* __restrict__ dst,
                                               const u64* __restrict__ lowW,
                                               const int* __restrict__ fprev,
                                               int* __restrict__ fcur,
                                               int* __restrict__ chg, int iter) {
  if (iter > 0 && chg[iter - 1] == 0) return;
  const int r = blockIdx.x + 12 * blockIdx.y + 144 * blockIdx.z;
  if (iter > 0) {
    bool act = false;
    for (int dz = -1; dz <= 1 && !act; ++dz) {
      int zz = (int)blockIdx.y + dz; if (zz < 0 || zz >= 12) continue;
      for (int dy = -1; dy <= 1; ++dy) {
        int yy = (int)blockIdx.x + dy; if (yy < 0 || yy >= 12) continue;
        if (fprev[yy + 12 * zz + 144 * blockIdx.z]) { act = true; break; }
      }
    }
    if (!act) { if (threadIdx.x == 0) fcur[r] = 0; return; }
  }

  __shared__ u64 sA[HLDS], sB[HLDS];
  __shared__ int blkC;
  const int t = threadIdx.x;
  if (t == 0) blkC = 0;
  const int y0 = blockIdx.x * HT - HH;
  const int z0 = blockIdx.y * HT - HH;
  const int b  = blockIdx.z;

  u64 lowr[4][3], orig[4][3];
#pragma unroll
  for (int j = 0; j < 4; ++j) {
    int l = t + 256 * j;
    int yy = l & 31, zz = l >> 5;
    int y = y0 + yy, z = z0 + zz;
    bool in = (y >= 0 && y < D3 && z >= 0 && z < D3);
    int wb = 3 * y + 576 * z + 110592 * b;
#pragma unroll
    for (int xw = 0; xw < 3; ++xw) {
      u64 sv = in ? src[wb + xw]  : 0ull;
      u64 lv = in ? lowW[wb + xw] : 0ull;
      sA[l * 3 + xw] = sv;
      orig[j][xw] = sv;
      lowr[j][xw] = lv;
    }
  }
  __syncthreads();

  u64* cur = sA; u64* nxt = sB;
  for (int s = 0; s < 8; ++s) {
#pragma unroll
    for (int j = 0; j < 4; ++j) {
      int l = t + 256 * j;
      int yy = l & 31, zz = l >> 5;
      int base = l * 3;
      u64 w0 = cur[base], w1 = cur[base + 1], w2 = cur[base + 2];
      u64 n0 = w0 | (w0 << 1) | (w0 >> 1) | (w1 << 63);
      u64 n1 = w1 | (w1 << 1) | (w1 >> 1) | (w0 >> 63) | (w2 << 63);
      u64 n2 = w2 | (w2 << 1) | (w2 >> 1) | (w1 >> 63);
      if (yy > 0)  { n0 |= cur[base - 3];  n1 |= cur[base - 2];  n2 |= cur[base - 1]; }
      if (yy < 31) { n0 |= cur[base + 3];  n1 |= cur[base + 4];  n2 |= cur[base + 5]; }
      if (zz > 0)  { n0 |= cur[base - 96]; n1 |= cur[base - 95]; n2 |= cur[base - 94]; }
      if (zz < 31) { n0 |= cur[base + 96]; n1 |= cur[base + 97]; n2 |= cur[base + 98]; }
      nxt[base]     = n0 & lowr[j][0];
      nxt[base + 1] = n1 & lowr[j][1];
      nxt[base + 2] = n2 & lowr[j][2];
    }
    __syncthreads();
    u64* tmp = cur; cur = nxt; nxt = tmp;
  }

  bool ch = false;
#pragma unroll
  for (int j = 0; j < 4; ++j) {
    int l = t + 256 * j;
    int yy = l & 31, zz = l >> 5;
    if (yy >= HH && yy < HH + HT && zz >= HH && zz < HH + HT) {
      int y = y0 + yy, z = z0 + zz;
      int wb = 3 * y + 576 * z + 110592 * b;
#pragma unroll
      for (int xw = 0; xw < 3; ++xw) {
        u64 o = cur[l * 3 + xw];
        ch |= (o != orig[j][xw]);
        dst[wb + xw] = o;
      }
    }
  }
  if (ch) blkC = 1;
  __syncthreads();
  if (t == 0) { fcur[r] = blkC; if (blkC) chg[iter] = 1; }
}

// fused z-closing (dilate r=1 then erode r=1, box SE), packed words
__global__ void __launch_bounds__(256) close_z_k(const u64* __restrict__ mi,
                                                 u64* __restrict__ mo) {
  int w = blockIdx.x * 256 + threadIdx.x;
  int z = (w / 576) % D3;
  u64 c   = mi[w];
  u64 zm1 = (z > 0)      ? mi[w - 576]  : 0ull;
  u64 zm2 = (z > 1)      ? mi[w - 1152] : 0ull;
  u64 zp1 = (z < D3 - 1) ? mi[w + 576]  : 0ull;
  u64 zp2 = (z < D3 - 2) ? mi[w + 1152] : 0ull;
  u64 d0 = c | zm1 | zp1;
  u64 e  = d0;
  if (z > 0)      e &= (zm2 | zm1 | c);
  if (z < D3 - 1) e &= (c | zp1 | zp2);
  mo[w] = e;
}

__global__ void __launch_bounds__(256) label_init_k(const u64* __restrict__ closedW,
                                                    int* __restrict__ lab) {
  int idx = blockIdx.x * 256 + threadIdx.x;
  int bit = (int)((closedW[idx >> 6] >> (idx & 63)) & 1ull);
  lab[idx] = bit ? (idx % NVOX) + 1 : 0;
}

__device__ __forceinline__ int imax2(int a, int b) { return a > b ? a : b; }

// One exact Jacobi step; voxel-granular changed-mask skip + summary (R6/R8 proven)
__global__ void __launch_bounds__(256) cc_word_k(const int* __restrict__ src,
                                                 int* __restrict__ dst,
                                                 const u64* __restrict__ chgPrev,
                                                 u64* __restrict__ chgCur,
                                                 const u64* __restrict__ sumPrev,
                                                 u64* __restrict__ sumCur,
                                                 const u64* __restrict__ closedW,
                                                 int* __restrict__ chg, int iter) {
  if (iter > 0 && chg[iter - 1] == 0) return;
  __shared__ int blkC;
  if (threadIdx.x == 0) blkC = 0;
  __syncthreads();

  const int w = blockIdx.x * 256 + threadIdx.x;
  const int xw = w % 3;
  const int y  = (w / 3) % D3;
  const int z  = (w / 576) % D3;

  u64 F, U;
  if (iter == 0) {
    F = ~0ull; U = 0ull;
  } else {
    u64 c  = ((sumPrev[w >> 6] >> (w & 63)) & 1ull) ? chgPrev[w] : 0ull;
    u64 cl = 0ull, cr = 0ull, ym = 0ull, yp = 0ull, zm = 0ull, zp = 0ull;
    if (xw > 0      && ((sumPrev[(w - 1) >> 6]   >> ((w - 1) & 63))   & 1ull)) cl = chgPrev[w - 1];
    if (xw < 2      && ((sumPrev[(w + 1) >> 6]   >> ((w + 1) & 63))   & 1ull)) cr = chgPrev[w + 1];
    if (y > 0       && ((sumPrev[(w - 3) >> 6]   >> ((w - 3) & 63))   & 1ull)) ym = chgPrev[w - 3];
    if (y < D3 - 1  && ((sumPrev[(w + 3) >> 6]   >> ((w + 3) & 63))   & 1ull)) yp = chgPrev[w + 3];
    if (z > 0       && ((sumPrev[(w - 576) >> 6] >> ((w - 576) & 63)) & 1ull)) zm = chgPrev[w - 576];
    if (z < D3 - 1  && ((sumPrev[(w + 576) >> 6] >> ((w + 576) & 63)) & 1ull)) zp = chgPrev[w + 576];
    u64 nb = (c << 1) | (c >> 1) | (cl >> 63) | (cr << 63) | ym | yp | zm | zp;
    if ((nb | c) == 0ull) { F = 0ull; U = 0ull; }
    else {
      u64 cw = closedW[w];
      F = nb & cw;
      U = c & cw & ~F;
    }
  }

  u64 P = F | U;
  u64 newc = 0;
  if (P) {
    int idx0 = xw * 64 + D3 * y + SZP * z + (w / 110592) * NVOX;
#pragma unroll
    for (int q = 0; q < 16; ++q) {
      if (!((P >> (4 * q)) & 0xFull)) continue;
      int idx = idx0 + 4 * q;
      int4 s = *(const int4*)(src + idx);
      int4 o = s;
      if ((F >> (4 * q)) & 0xFull) {
        int x = xw * 64 + 4 * q;
        const int4 z4 = make_int4(0, 0, 0, 0);
        int4 yv = (y > 0)      ? *(const int4*)(src + idx - D3)  : z4;
        int4 yw = (y < D3 - 1) ? *(const int4*)(src + idx + D3)  : z4;
        int4 zv = (z > 0)      ? *(const int4*)(src + idx - SZP) : z4;
        int4 zw = (z < D3 - 1) ? *(const int4*)(src + idx + SZP) : z4;
        int lf = (x > 0)       ? src[idx - 1] : 0;
        int rt = (x < D3 - 4)  ? src[idx + 4] : 0;
        o.x = s.x ? imax2(imax2(imax2(s.x, lf),  imax2(s.y, yv.x)), imax2(imax2(yw.x, zv.x), zw.x)) : 0;
        o.y = s.y ? imax2(imax2(imax2(s.y, s.x), imax2(s.z, yv.y)), imax2(imax2(yw.y, zv.y), zw.y)) : 0;
        o.z = s.z ? imax2(imax2(imax2(s.z, s.y), imax2(s.w, yv.z)), imax2(imax2(yw.z, zv.z), zw.z)) : 0;
        o.w = s.w ? imax2(imax2(imax2(s.w, s.z), imax2(rt,  yv.w)), imax2(imax2(yw.w, zv.w), zw.w)) : 0;
      }
      *(int4*)(dst + idx) = o;
      u64 df = (u64)((o.x != s.x) | ((o.y != s.y) << 1) |
                     ((o.z != s.z) << 2) | ((o.w != s.w) << 3));
      newc |= df << (4 * q);
    }
  }

  u64 bal = __ballot(newc != 0ull);
  if (newc) chgCur[w] = newc;
  if ((threadIdx.x & 63) == 0) sumCur[w >> 6] = bal;
  if (bal) blkC = 1;
  __syncthreads();
  if (threadIdx.x == 0 && blkC) chg[iter] = 1;
}

// project step-12 voxel-changed bitmap onto cc4 region flags (one wave/region)
__global__ void __launch_bounds__(256) proj_k(const u64* __restrict__ chgW,
                                              const u64* __restrict__ sumW,
                                              int* __restrict__ freg) {
  int reg = blockIdx.x * 4 + (threadIdx.x >> 6);
  int lane = threadIdx.x & 63;
  int bx = reg % 6; int t2 = reg / 6;
  int by = t2 % 24; int t3 = t2 / 24;
  int bz = t3 % 24; int b = t3 / 24;
  int ly = lane & 7, lz = lane >> 3;
  int y = by * 8 + ly, z = bz * 8 + lz;
  int w = (bx >> 1) + 3 * y + 576 * z + 110592 * b;
  u64 m = ((sumW[w >> 6] >> (w & 63)) & 1ull) ? chgW[w] : 0ull;
  u64 mask = (bx & 1) ? 0xFFFFFFFF00000000ull : 0x00000000FFFFFFFFull;
  u64 bal = __ballot((m & mask) != 0ull);
  if (lane == 0) freg[reg] = (bal != 0ull) ? 1 : 0;
}

// 4 exact Jacobi steps per dispatch (R7-proven halo-4 LDS tile), region-27-hood
// skip via flag chain (handoff flags seeded by proj_k). gate/setf generalize
// the chg chain across the cc_word -> cc4 boundary.
__global__ void __launch_bounds__(256) cc4_k(const int* __restrict__ src,
                                             int* __restrict__ dst,
                                             const int* __restrict__ fprev,
                                             int* __restrict__ fcur,
                                             const int* __restrict__ gate,
                                             int* __restrict__ setf) {
  if (*gate == 0) return;
  const int bx = blockIdx.x, by = blockIdx.y;
  const int bz = blockIdx.z % 24, b = blockIdx.z / 24;
  const int r = bx + 6 * by + 144 * bz + 3456 * b;

  bool act = false;
  for (int dz = -1; dz <= 1 && !act; ++dz) {
    int zz = bz + dz; if (zz < 0 || zz >= 24) continue;
    for (int dy = -1; dy <= 1 && !act; ++dy) {
      int yy = by + dy; if (yy < 0 || yy >= 24) continue;
      for (int dx = -1; dx <= 1; ++dx) {
        int xx = bx + dx; if (xx < 0 || xx >= 6) continue;
        if (fprev[xx + 6 * yy + 144 * zz + 3456 * b]) { act = true; break; }
      }
    }
  }
  if (!act) { if (threadIdx.x == 0) fcur[r] = 0; return; }

  __shared__ int sL[CRN];
  __shared__ int chStep;
  const int t = threadIdx.x;
  const int gx0 = bx * 32 - 4, gy0 = by * 8 - 4, gz0 = bz * 8 - 4;

  u64 mxlo = 0, mxhi = 0, mylo = 0, myhi = 0, mzlo = 0, mzhi = 0;
  int val[CJ];
#pragma unroll
  for (int j = 0; j < CJ; ++j) {
    int l = t + 256 * j;
    int x = l % CRX; int rr = l / CRX; int y = rr % CRY; int z = rr / CRY;
    int gx = gx0 + x, gy = gy0 + y, gz = gz0 + z;
    int vv = 0;
    if (gx >= 0 && gx < D3 && gy >= 0 && gy < D3 && gz >= 0 && gz < D3)
      vv = src[gx + D3 * gy + SZP * gz + b * NVOX];
    sL[l] = vv;
    val[j] = vv;
    mxlo |= ((u64)(x > 0))       << j;  mxhi |= ((u64)(x < CRX - 1)) << j;
    mylo |= ((u64)(y > 0))       << j;  myhi |= ((u64)(y < CRY - 1)) << j;
    mzlo |= ((u64)(z > 0))       << j;  mzhi |= ((u64)(z < CRZ - 1)) << j;
  }

  bool anyC = false;
  for (int s = 0; s < 4; ++s) {
    if (t == 0) chStep = 0;
    __syncthreads();
    bool ch = false;
#pragma unroll
    for (int j = 0; j < CJ; ++j) {
      int l = t + 256 * j;
      int vv = sL[l];
      int o = vv;
      if (vv > 0) {
        if ((mxlo >> j) & 1) o = imax2(o, sL[l - 1]);
        if ((mxhi >> j) & 1) o = imax2(o, sL[l + 1]);
        if ((mylo >> j) & 1) o = imax2(o, sL[l - CRX]);
        if ((myhi >> j) & 1) o = imax2(o, sL[l + CRX]);
        if ((mzlo >> j) & 1) o = imax2(o, sL[l - CRX * CRY]);
        if ((mzhi >> j) & 1) o = imax2(o, sL[l + CRX * CRY]);
        ch |= (o != vv);
      }
      val[j] = o;
    }
    if (ch) chStep = 1;
    __syncthreads();
    if (chStep == 0) break;
    anyC = true;
#pragma unroll
    for (int j = 0; j < CJ; ++j) {
      int l = t + 256 * j;
      if (val[j] != 0) sL[l] = val[j];
    }
  }

#pragma unroll
  for (int j = 0; j < CJ; ++j) {
    int l = t + 256 * j;
    int x = l % CRX; int rr = l / CRX; int y = rr % CRY; int z = rr / CRY;
    if (x >= 4 && x < 36 && y >= 4 && y < 12 && z >= 4 && z < 12) {
      int gx = gx0 + x, gy = gy0 + y, gz = gz0 + z;
      dst[gx + D3 * gy + SZP * gz + b * NVOX] = val[j];
    }
  }
  if (t == 0) { fcur[r] = anyC ? 1 : 0; if (anyC) *setf = 1; }
}

__global__ void __launch_bounds__(256) count_k(const int* __restrict__ lab,
                                               unsigned int* __restrict__ counts) {
  int q = blockIdx.x * 256 + threadIdx.x;
  int idx = q << 2;
  int b = idx / NVOX;
  int4 L = *(const int4*)(lab + idx);
  unsigned int* cb = counts + (size_t)b * NVOX;
  if (L.x > 0) atomicAdd(&cb[L.x - 1], 1u);
  if (L.y > 0) atomicAdd(&cb[L.y - 1], 1u);
  if (L.z > 0) atomicAdd(&cb[L.z - 1], 1u);
  if (L.w > 0) atomicAdd(&cb[L.w - 1], 1u);
}

__global__ void __launch_bounds__(256) final_k(const int* __restrict__ lab,
                                               const unsigned int* __restrict__ counts,
                                               float* __restrict__ out) {
  int q = blockIdx.x * 256 + threadIdx.x;
  int idx = q << 2;
  int b = idx / NVOX;
  int4 L = *(const int4*)(lab + idx);
  const unsigned int* cb = counts + (size_t)b * NVOX;
  float4 rr;
  rr.x = (L.x > 0 && cb[L.x - 1] >= 100u) ? 1.f : 0.f;
  rr.y = (L.y > 0 && cb[L.y - 1] >= 100u) ? 1.f : 0.f;
  rr.z = (L.z > 0 && cb[L.z - 1] >= 100u) ? 1.f : 0.f;
  rr.w = (L.w > 0 && cb[L.w - 1] >= 100u) ? 1.f : 0.f;
  *(float4*)(out + idx) = rr;
}

// ---- host-side: emulate numpy f32 pairwise sum exactly ----
static float np_sum_f32(const float* a, int n) {
  if (n < 8) { float res = 0.f; for (int i = 0; i < n; i++) res += a[i]; return res; }
  float r[8]; for (int j = 0; j < 8; j++) r[j] = a[j];
  int i = 8;
  for (; i < n - (n % 8); i += 8) for (int j = 0; j < 8; j++) r[j] += a[i + j];
  float res = ((r[0] + r[1]) + (r[2] + r[3])) + ((r[4] + r[5]) + (r[6] + r[7]));
  for (; i < n; i++) res += a[i];
  return res;
}

extern "C" void kernel_launch(void* const* d_in, const int* in_sizes, int n_in,
                              void* d_out, int out_size, void* d_ws, size_t ws_size,
                              hipStream_t stream) {
  const float* v = (const float*)d_in[0];
  float* out = (float*)d_out;
  char* base = (char*)d_ws;
  const size_t SZBUF = (size_t)NTOT * 4;     // 56.6 MB
  const size_t SZW   = (size_t)W3 * 8;       // 1.77 MB

  float* A  = (float*)base;
  float* Cf = (float*)(base + SZBUF);
  unsigned int* mx = (unsigned int*)(base + 2 * SZBUF);
  float* bmax = (float*)(base + 2 * SZBUF + 256);
  float* Bf = (float*)d_out;

  u64* lowW    = (u64*)base;
  u64* mWA     = (u64*)(base + SZW);
  u64* mWB     = (u64*)(base + 2 * SZW);
  u64* closedW = (u64*)(base + 3 * SZW);
  u64* chgWA   = (u64*)(base + 4 * SZW);
  u64* chgWB   = (u64*)(base + 5 * SZW);
  u64* sumA    = (u64*)(base + 6 * SZW);
  u64* sumB    = sumA + NSUM;
  int* chgH   = (int*)(sumB + NSUM);       // 32
  int* chgC   = chgH + 32;                 // 256
  int* hF0    = chgC + 256;                // 288
  int* hF1    = hF0 + NHT;                 // 288
  int* cF0    = hF1 + NHT;                 // 6912
  int* cF1    = cF0 + NCT;                 // 6912
  int* cc4chg = cF1 + NCT;                 // 64
  size_t ctrlBytes = (char*)(cc4chg + 64) - (char*)chgH;

  int* labA = (int*)Bf;
  int* labB = (int*)Cf;
  unsigned int* counts = (unsigned int*)base;   // masks dead after CC -> reuse

  dim3 g(NBLK), gw(WBLK), gq(NQB), blk(256);

  const double sigmas[2] = {1.0, 2.0};
  for (int si = 0; si < 2; ++si) {
    double sigma = sigmas[si];
    int r = (int)(3.0 * sigma + 0.5);
    int n = 2 * r + 1;
    float a[13], k[13];
    for (int i = 0; i < n; i++) {
      float xx = (float)(i - r);
      float t  = xx * xx;
      float arg = -(t) / (float)(2.0 * sigma * sigma);
      a[i] = (float)std::exp((double)arg);
    }
    float ssum = np_sum_f32(a, n);
    for (int i = 0; i < n; i++) k[i] = a[i] / ssum;

    Taps13 T = {};
    for (int i = 0; i < n; i++) T.k[i] = k[i];
    float scale = (float)(sigma * sigma);
    float* starget = (si == 0) ? Cf : Bf;

    if (r == 3) {
      conv1d_k<0, 3><<<g, blk, 0, stream>>>(v,  A,  T);
      conv1d_k<1, 3><<<g, blk, 0, stream>>>(A,  Bf, T);
      conv1d_k<2, 3><<<g, blk, 0, stream>>>(Bf, A,  T);
    } else {
      conv1d_k<0, 6><<<g, blk, 0, stream>>>(v,  A,  T);
      conv1d_k<1, 6><<<g, blk, 0, stream>>>(A,  Bf, T);
      conv1d_k<2, 6><<<g, blk, 0, stream>>>(Bf, A,  T);
    }
    surf_k<<<g, blk, 0, stream>>>(A, starget, bmax, scale);
    reduce_max_k<<<dim3(2), blk, 0, stream>>>(bmax, mx + 2 * si);
  }

  // A's f32 data dead from here; packed masks / flags reuse its footprint.
  hipMemsetAsync(chgH, 0, ctrlBytes, stream);
  mask_init_pack_k<<<g, blk, 0, stream>>>(v, Cf, Bf, mx, lowW, mWA);

  // hysteresis: 32 x (8 exact steps) == F^256, tile-skip + global early-exit
  for (int it = 0; it < 32; ++it) {
    const u64* s = (it & 1) ? mWB : mWA;
    u64*       d = (it & 1) ? mWA : mWB;
    const int* fp = (it & 1) ? hF0 : hF1;
    int*       fc = (it & 1) ? hF1 : hF0;
    hyst8_k<<<dim3(12, 12, 2), blk, 0, stream>>>(s, d, lowW, fp, fc, chgH, it);
  }
  // state in mWA (or both equal if converged early)

  close_z_k<<<gw, blk, 0, stream>>>(mWA, closedW);

  // CC phase 1: 12 x 1-step cc_word (dense), voxel skip + summary
  label_init_k<<<g, blk, 0, stream>>>(closedW, labA);
  for (int it = 0; it < 12; ++it) {
    const int* s = (it & 1) ? labB : labA;
    int*       d = (it & 1) ? labA : labB;
    const u64* cp = (it & 1) ? chgWB : chgWA;
    u64*       cc = (it & 1) ? chgWA : chgWB;
    const u64* sp = (it & 1) ? sumB : sumA;
    u64*       sc = (it & 1) ? sumA : sumB;
    cc_word_k<<<gw, blk, 0, stream>>>(s, d, cp, cc, sp, sc, closedW, chgC, it);
  }
  // after 12 steps: S_12 in labA, S_11 in labB, changes in chgWA/sumA

  // seed region flags for cc4 from the step-12 changed bitmap
  proj_k<<<dim3(NCT / 4), blk, 0, stream>>>(chgWA, sumA, cF0);

  // CC phase 2: 61 x (4 exact steps) -> total 12 + 244 = 256
  for (int j = 0; j < 61; ++j) {
    const int* s = (j & 1) ? labB : labA;
    int*       d = (j & 1) ? labA : labB;
    const int* fp = (j & 1) ? cF1 : cF0;
    int*       fc = (j & 1) ? cF0 : cF1;
    const int* gate = (j == 0) ? &chgC[11] : &cc4chg[j - 1];
    cc4_k<<<dim3(6, 24, 48), blk, 0, stream>>>(s, d, fp, fc, gate, &cc4chg[j]);
  }
  // 61 swaps (odd) -> final labels in labB (or both equal if converged)

  hipMemsetAsync(counts, 0, SZBUF, stream);
  count_k<<<gq, blk, 0, stream>>>(labB, counts);
  final_k<<<gq, blk, 0, stream>>>(labB, counts, out);
}

// Round 11
// 1613.074 us; speedup vs baseline: 2.6493x; 1.5340x over previous
//
#include <hip/hip_runtime.h>
#include <cmath>

#define D3   192
#define SZP  (D3*D3)        // 36864, z stride
#define NVOX (D3*D3*D3)     // 7077888
#define NTOT (2*NVOX)       // 14155776
#define NBLK (NTOT/256)     // 55296
#define W3   (NTOT/64)      // 221184 packed words total
#define WBLK (W3/256)       // 864
#define NSUM (W3/64)        // 3456 summary words
#define NQ   (NTOT/4)       // quads
#define NQB  (NQ/256)       // 13824
#define BPB  (NVOX/256)     // 27648 blocks per volume

// hysteresis multi-step tile
#define HT 16
#define HH 8
#define HL (HT+2*HH)        // 32
#define HLDS (HL*HL*3)      // 3072 u64 (24 KB per buffer)
#define NHT  (12*12*2)      // 288 tiles

typedef unsigned long long u64;

struct Taps13 { float k[13]; };

__device__ __forceinline__ void coords(int idx, int& x, int& y, int& z, int& b) {
  x = idx % D3;
  y = (idx / D3) % D3;
  z = (idx / SZP) % D3;
  b = idx / NVOX;
}

// 1D 'same' zero-padded correlation along AXIS; accumulation order i=-R..R
// with separate rn mul/add to match XLA's un-contracted  out = out + k[i]*v.
template<int AXIS, int R>
__global__ void __launch_bounds__(256) conv1d_k(const float* __restrict__ in,
                                                float* __restrict__ out, Taps13 t) {
  int idx = blockIdx.x * 256 + threadIdx.x;
  int x, y, z, b; coords(idx, x, y, z, b);
  int c = (AXIS == 0) ? z : (AXIS == 1) ? y : x;
  const int stride = (AXIS == 0) ? SZP : (AXIS == 1) ? D3 : 1;
  float acc = 0.f;
#pragma unroll
  for (int i = -R; i <= R; ++i) {
    int cc = c + i;
    if (cc >= 0 && cc < D3)
      acc = __fadd_rn(acc, __fmul_rn(t.k[i + R], in[idx + i * stride]));
  }
  out[idx] = acc;
}

// fused fxx/fyy/fzz + surfaceness; per-BLOCK max to bmax (plain store)
__global__ void __launch_bounds__(256) surf_k(const float* __restrict__ s,
                                              float* __restrict__ surf,
                                              float* __restrict__ bmax,
                                              float scale) {
  int idx = blockIdx.x * 256 + threadIdx.x;
  int x, y, z, b; coords(idx, x, y, z, b);
  float ctr = s[idx];
  float fxx, fyy, fzz;
  { float acc = 0.f;
    if (z > 0)      acc = __fadd_rn(acc, __fmul_rn(1.f, s[idx - SZP]));
    acc = __fadd_rn(acc, __fmul_rn(-2.f, ctr));
    if (z < D3 - 1) acc = __fadd_rn(acc, __fmul_rn(1.f, s[idx + SZP]));
    fxx = __fmul_rn(acc, scale); }
  { float acc = 0.f;
    if (y > 0)      acc = __fadd_rn(acc, __fmul_rn(1.f, s[idx - D3]));
    acc = __fadd_rn(acc, __fmul_rn(-2.f, ctr));
    if (y < D3 - 1) acc = __fadd_rn(acc, __fmul_rn(1.f, s[idx + D3]));
    fyy = __fmul_rn(acc, scale); }
  { float acc = 0.f;
    if (x > 0)      acc = __fadd_rn(acc, __fmul_rn(1.f, s[idx - 1]));
    acc = __fadd_rn(acc, __fmul_rn(-2.f, ctr));
    if (x < D3 - 1) acc = __fadd_rn(acc, __fmul_rn(1.f, s[idx + 1]));
    fzz = __fmul_rn(acc, scale); }

  float num = __fadd_rn(__fmul_rn(fxx, fxx), __fmul_rn(fyy, fyy));
  float den = __fmul_rn(0.25f, __fadd_rn(__fmul_rn(fzz, fzz), 1e-7f));
  float arg = __fdiv_rn(-num, den);
  float sv  = __fmul_rn(expf(arg), fabsf(fzz));
  surf[idx] = sv;

  float m = sv;
  #pragma unroll
  for (int off = 32; off > 0; off >>= 1) m = fmaxf(m, __shfl_down(m, off));
  __shared__ float wred[4];
  int lane = threadIdx.x & 63, wid = threadIdx.x >> 6;
  if (lane == 0) wred[wid] = m;
  __syncthreads();
  if (threadIdx.x == 0)
    bmax[blockIdx.x] = fmaxf(fmaxf(wred[0], wred[1]), fmaxf(wred[2], wred[3]));
}

__global__ void __launch_bounds__(256) reduce_max_k(const float* __restrict__ bmax,
                                                    unsigned int* __restrict__ mxp) {
  int b = blockIdx.x;
  const float* p = bmax + b * BPB;
  float m = 0.f;
  for (int i = threadIdx.x; i < BPB; i += 256) m = fmaxf(m, p[i]);
  #pragma unroll
  for (int off = 32; off > 0; off >>= 1) m = fmaxf(m, __shfl_down(m, off));
  __shared__ float wred[4];
  int lane = threadIdx.x & 63, wid = threadIdx.x >> 6;
  if (lane == 0) wred[wid] = m;
  __syncthreads();
  if (threadIdx.x == 0)
    mxp[b] = __float_as_uint(fmaxf(fmaxf(wred[0], wred[1]), fmaxf(wred[2], wred[3])));
}

__global__ void __launch_bounds__(256) mask_init_pack_k(const float* __restrict__ v,
                                                        const float* __restrict__ s1,
                                                        const float* __restrict__ s2,
                                                        const unsigned int* __restrict__ mx,
                                                        u64* __restrict__ lowW,
                                                        u64* __restrict__ mW) {
  int idx = blockIdx.x * 256 + threadIdx.x;
  int b = idx / NVOX;
  float m1 = __uint_as_float(mx[b]);
  float m2 = __uint_as_float(mx[2 + b]);
  float n1 = (m1 > 0.f) ? __fdiv_rn(s1[idx], __fadd_rn(m1, 1e-7f)) : 0.f;
  float n2 = (m2 > 0.f) ? __fdiv_rn(s2[idx], __fadd_rn(m2, 1e-7f)) : 0.f;
  float vol = __fmul_rn(v[idx], fmaxf(n1, n2));
  u64 bl = __ballot(vol > 0.5f);
  u64 bh = __ballot(vol > 0.9f);
  if ((threadIdx.x & 63) == 0) {
    lowW[idx >> 6] = bl;
    mW[idx >> 6]   = bh;
  }
}

// 8 exact flood-fill steps per dispatch (halo-8 LDS tile), tile-level 9-hood skip
__global__ void __launch_bounds__(256) hyst8_k(const u64* __restrict__ src,
                                               u64* __restrict__ dst,
                                               const u64* __restrict__ lowW,
                                               const int* __restrict__ fprev,
                                               int* __restrict__ fcur,
                                               int* __restrict__ chg, int iter) {
  if (iter > 0 && chg[iter - 1] == 0) return;
  const int r = blockIdx.x + 12 * blockIdx.y + 144 * blockIdx.z;
  if (iter > 0) {
    bool act = false;
    for (int dz = -1; dz <= 1 && !act; ++dz) {
      int zz = (int)blockIdx.y + dz; if (zz < 0 || zz >= 12) continue;
      for (int dy = -1; dy <= 1; ++dy) {
        int yy = (int)blockIdx.x + dy; if (yy < 0 || yy >= 12) continue;
        if (fprev[yy + 12 * zz + 144 * blockIdx.z]) { act = true; break; }
      }
    }
    if (!act) { if (threadIdx.x == 0) fcur[r] = 0; return; }
  }

  __shared__ u64 sA[HLDS], sB[HLDS];
  __shared__ int blkC;
  const int t = threadIdx.x;
  if (t == 0) blkC = 0;
  const int y0 = blockIdx.x * HT - HH;
  const int z0 = blockIdx.y * HT - HH;
  const int b  = blockIdx.z;

  u64 lowr[4][3], orig[4][3];
#pragma unroll
  for (int j = 0; j < 4; ++j) {
    int l = t + 256 * j;
    int yy = l & 31, zz = l >> 5;
    int y = y0 + yy, z = z0 + zz;
    bool in = (y >= 0 && y < D3 && z >= 0 && z < D3);
    int wb = 3 * y + 576 * z + 110592 * b;
#pragma unroll
    for (int xw = 0; xw < 3; ++xw) {
      u64 sv = in ? src[wb + xw]  : 0ull;
      u64 lv = in ? lowW[wb + xw] : 0ull;
      sA[l * 3 + xw] = sv;
      orig[j][xw] = sv;
      lowr[j][xw] = lv;
    }
  }
  __syncthreads();

  u64* cur = sA; u64* nxt = sB;
  for (int s = 0; s < 8; ++s) {
#pragma unroll
    for (int j = 0; j < 4; ++j) {
      int l = t + 256 * j;
      int yy = l & 31, zz = l >> 5;
      int base = l * 3;
      u64 w0 = cur[base], w1 = cur[base + 1], w2 = cur[base + 2];
      u64 n0 = w0 | (w0 << 1) | (w0 >> 1) | (w1 << 63);
      u64 n1 = w1 | (w1 << 1) | (w1 >> 1) | (w0 >> 63) | (w2 << 63);
      u64 n2 = w2 | (w2 << 1) | (w2 >> 1) | (w1 >> 63);
      if (yy > 0)  { n0 |= cur[base - 3];  n1 |= cur[base - 2];  n2 |= cur[base - 1]; }
      if (yy < 31) { n0 |= cur[base + 3];  n1 |= cur[base + 4];  n2 |= cur[base + 5]; }
      if (zz > 0)  { n0 |= cur[base - 96]; n1 |= cur[base - 95]; n2 |= cur[base - 94]; }
      if (zz < 31) { n0 |= cur[base + 96]; n1 |= cur[base + 97]; n2 |= cur[base + 98]; }
      nxt[base]     = n0 & lowr[j][0];
      nxt[base + 1] = n1 & lowr[j][1];
      nxt[base + 2] = n2 & lowr[j][2];
    }
    __syncthreads();
    u64* tmp = cur; cur = nxt; nxt = tmp;
  }

  bool ch = false;
#pragma unroll
  for (int j = 0; j < 4; ++j) {
    int l = t + 256 * j;
    int yy = l & 31, zz = l >> 5;
    if (yy >= HH && yy < HH + HT && zz >= HH && zz < HH + HT) {
      int y = y0 + yy, z = z0 + zz;
      int wb = 3 * y + 576 * z + 110592 * b;
#pragma unroll
      for (int xw = 0; xw < 3; ++xw) {
        u64 o = cur[l * 3 + xw];
        ch |= (o != orig[j][xw]);
        dst[wb + xw] = o;
      }
    }
  }
  if (ch) blkC = 1;
  __syncthreads();
  if (t == 0) { fcur[r] = blkC; if (blkC) chg[iter] = 1; }
}

// fused z-closing (dilate r=1 then erode r=1, box SE), packed words
__global__ void __launch_bounds__(256) close_z_k(const u64* __restrict__ mi,
                                                 u64* __restrict__ mo) {
  int w = blockIdx.x * 256 + threadIdx.x;
  int z = (w / 576) % D3;
  u64 c   = mi[w];
  u64 zm1 = (z > 0)      ? mi[w - 576]  : 0ull;
  u64 zm2 = (z > 1)      ? mi[w - 1152] : 0ull;
  u64 zp1 = (z < D3 - 1) ? mi[w + 576]  : 0ull;
  u64 zp2 = (z < D3 - 2) ? mi[w + 1152] : 0ull;
  u64 d0 = c | zm1 | zp1;
  u64 e  = d0;
  if (z > 0)      e &= (zm2 | zm1 | c);
  if (z < D3 - 1) e &= (c | zp1 | zp2);
  mo[w] = e;
}

// Fused label-init + first Jacobi step, pure bit-ops on closedW.
// Init labels are strictly index-ordered, so max over present neighbors is
//   o = L + (z+1 set ? 36864 : y+1 set ? 192 : x+1 set ? 1 : 0)
// (z-1/y-1/x-1/own are all smaller). Writes S_0 -> lab0 (labA), S_1 -> lab1
// (labB), changed bits -> chgW/sumW (same convention as cc_word iter 0).
__global__ void __launch_bounds__(256) cc_init_fused_k(const u64* __restrict__ closedW,
                                                       int* __restrict__ lab0,
                                                       int* __restrict__ lab1,
                                                       u64* __restrict__ chgW,
                                                       u64* __restrict__ sumW,
                                                       int* __restrict__ chg) {
  __shared__ int blkC;
  if (threadIdx.x == 0) blkC = 0;
  __syncthreads();
  const int w = blockIdx.x * 256 + threadIdx.x;
  const int xw = w % 3;
  const int y  = (w / 3) % D3;
  const int z  = (w / 576) % D3;
  u64 cw = closedW[w];
  u64 xp = cw >> 1;
  if (xw < 2) xp |= (closedW[w + 1] & 1ull) << 63;
  u64 yp = (y < D3 - 1) ? closedW[w + 3]   : 0ull;
  u64 zp = (z < D3 - 1) ? closedW[w + 576] : 0ull;
  u64 newc = cw & (xp | yp | zp);

  const int rel0  = xw * 64 + D3 * y + SZP * z;       // linear-in-volume idx of bit 0
  const int vbase = rel0 + (w / 110592) * NVOX;        // global idx of bit 0
#pragma unroll
  for (int q = 0; q < 16; ++q) {
    int sh = 4 * q;
    unsigned nib = (unsigned)((cw >> sh) & 0xFull);
    int4 s0 = make_int4(0, 0, 0, 0), s1 = make_int4(0, 0, 0, 0);
    if (nib) {
      unsigned nxp = (unsigned)((xp >> sh) & 0xFull);
      unsigned nyp = (unsigned)((yp >> sh) & 0xFull);
      unsigned nzp = (unsigned)((zp >> sh) & 0xFull);
      int L0 = rel0 + sh + 1;
      if (nib & 1u) { s0.x = L0;     s1.x = L0     + ((nzp & 1u) ? SZP : (nyp & 1u) ? D3 : (nxp & 1u) ? 1 : 0); }
      if (nib & 2u) { s0.y = L0 + 1; s1.y = L0 + 1 + ((nzp & 2u) ? SZP : (nyp & 2u) ? D3 : (nxp & 2u) ? 1 : 0); }
      if (nib & 4u) { s0.z = L0 + 2; s1.z = L0 + 2 + ((nzp & 4u) ? SZP : (nyp & 4u) ? D3 : (nxp & 4u) ? 1 : 0); }
      if (nib & 8u) { s0.w = L0 + 3; s1.w = L0 + 3 + ((nzp & 8u) ? SZP : (nyp & 8u) ? D3 : (nxp & 8u) ? 1 : 0); }
    }
    *(int4*)(lab0 + vbase + sh) = s0;
    *(int4*)(lab1 + vbase + sh) = s1;
  }

  u64 bal = __ballot(newc != 0ull);
  if (newc) chgW[w] = newc;
  if ((threadIdx.x & 63) == 0) sumW[w >> 6] = bal;
  if (bal) blkC = 1;
  __syncthreads();
  if (threadIdx.x == 0 && blkC) chg[0] = 1;
}

__device__ __forceinline__ int imax2(int a, int b) { return a > b ? a : b; }

// One exact Jacobi step; voxel-granular changed-mask skip + summary (R6/R8 proven)
__global__ void __launch_bounds__(256) cc_word_k(const int* __restrict__ src,
                                                 int* __restrict__ dst,
                                                 const u64* __restrict__ chgPrev,
                                                 u64* __restrict__ chgCur,
                                                 const u64* __restrict__ sumPrev,
                                                 u64* __restrict__ sumCur,
                                                 const u64* __restrict__ closedW,
                                                 int* __restrict__ chg, int iter) {
  if (iter > 0 && chg[iter - 1] == 0) return;
  __shared__ int blkC;
  if (threadIdx.x == 0) blkC = 0;
  __syncthreads();

  const int w = blockIdx.x * 256 + threadIdx.x;
  const int xw = w % 3;
  const int y  = (w / 3) % D3;
  const int z  = (w / 576) % D3;

  u64 F, U;
  {
    u64 c  = ((sumPrev[w >> 6] >> (w & 63)) & 1ull) ? chgPrev[w] : 0ull;
    u64 cl = 0ull, cr = 0ull, ym = 0ull, yp = 0ull, zm = 0ull, zp = 0ull;
    if (xw > 0      && ((sumPrev[(w - 1) >> 6]   >> ((w - 1) & 63))   & 1ull)) cl = chgPrev[w - 1];
    if (xw < 2      && ((sumPrev[(w + 1) >> 6]   >> ((w + 1) & 63))   & 1ull)) cr = chgPrev[w + 1];
    if (y > 0       && ((sumPrev[(w - 3) >> 6]   >> ((w - 3) & 63))   & 1ull)) ym = chgPrev[w - 3];
    if (y < D3 - 1  && ((sumPrev[(w + 3) >> 6]   >> ((w + 3) & 63))   & 1ull)) yp = chgPrev[w + 3];
    if (z > 0       && ((sumPrev[(w - 576) >> 6] >> ((w - 576) & 63)) & 1ull)) zm = chgPrev[w - 576];
    if (z < D3 - 1  && ((sumPrev[(w + 576) >> 6] >> ((w + 576) & 63)) & 1ull)) zp = chgPrev[w + 576];
    u64 nb = (c << 1) | (c >> 1) | (cl >> 63) | (cr << 63) | ym | yp | zm | zp;
    if ((nb | c) == 0ull) { F = 0ull; U = 0ull; }
    else {
      u64 cw = closedW[w];
      F = nb & cw;
      U = c & cw & ~F;
    }
  }

  u64 P = F | U;
  u64 newc = 0;
  if (P) {
    int idx0 = xw * 64 + D3 * y + SZP * z + (w / 110592) * NVOX;
#pragma unroll
    for (int q = 0; q < 16; ++q) {
      if (!((P >> (4 * q)) & 0xFull)) continue;
      int idx = idx0 + 4 * q;
      int4 s = *(const int4*)(src + idx);
      int4 o = s;
      if ((F >> (4 * q)) & 0xFull) {
        int x = xw * 64 + 4 * q;
        const int4 z4 = make_int4(0, 0, 0, 0);
        int4 yv = (y > 0)      ? *(const int4*)(src + idx - D3)  : z4;
        int4 yw = (y < D3 - 1) ? *(const int4*)(src + idx + D3)  : z4;
        int4 zv = (z > 0)      ? *(const int4*)(src + idx - SZP) : z4;
        int4 zw = (z < D3 - 1) ? *(const int4*)(src + idx + SZP) : z4;
        int lf = (x > 0)       ? src[idx - 1] : 0;
        int rt = (x < D3 - 4)  ? src[idx + 4] : 0;
        o.x = s.x ? imax2(imax2(imax2(s.x, lf),  imax2(s.y, yv.x)), imax2(imax2(yw.x, zv.x), zw.x)) : 0;
        o.y = s.y ? imax2(imax2(imax2(s.y, s.x), imax2(s.z, yv.y)), imax2(imax2(yw.y, zv.y), zw.y)) : 0;
        o.z = s.z ? imax2(imax2(imax2(s.z, s.y), imax2(s.w, yv.z)), imax2(imax2(yw.z, zv.z), zw.z)) : 0;
        o.w = s.w ? imax2(imax2(imax2(s.w, s.z), imax2(rt,  yv.w)), imax2(imax2(yw.w, zv.w), zw.w)) : 0;
      }
      *(int4*)(dst + idx) = o;
      u64 df = (u64)((o.x != s.x) | ((o.y != s.y) << 1) |
                     ((o.z != s.z) << 2) | ((o.w != s.w) << 3));
      newc |= df << (4 * q);
    }
  }

  u64 bal = __ballot(newc != 0ull);
  if (newc) chgCur[w] = newc;
  if ((threadIdx.x & 63) == 0) sumCur[w >> 6] = bal;
  if (bal) blkC = 1;
  __syncthreads();
  if (threadIdx.x == 0 && blkC) chg[iter] = 1;
}

__global__ void __launch_bounds__(256) count_k(const int* __restrict__ lab,
                                               const u64* __restrict__ closedW,
                                               unsigned int* __restrict__ counts) {
  int q = blockIdx.x * 256 + threadIdx.x;
  int idx = q << 2;
  u64 cw = closedW[idx >> 6];                  // near-uniform per wave
  unsigned nib = (unsigned)((cw >> (idx & 63)) & 0xFull);
  if (!nib) return;
  int b = idx / NVOX;
  int4 L = *(const int4*)(lab + idx);
  unsigned int* cb = counts + (size_t)b * NVOX;
  if (L.x > 0) atomicAdd(&cb[L.x - 1], 1u);
  if (L.y > 0) atomicAdd(&cb[L.y - 1], 1u);
  if (L.z > 0) atomicAdd(&cb[L.z - 1], 1u);
  if (L.w > 0) atomicAdd(&cb[L.w - 1], 1u);
}

__global__ void __launch_bounds__(256) final_k(const int* __restrict__ lab,
                                               const u64* __restrict__ closedW,
                                               const unsigned int* __restrict__ counts,
                                               float* __restrict__ out) {
  int q = blockIdx.x * 256 + threadIdx.x;
  int idx = q << 2;
  u64 cw = closedW[idx >> 6];
  unsigned nib = (unsigned)((cw >> (idx & 63)) & 0xFull);
  float4 rr = make_float4(0.f, 0.f, 0.f, 0.f);
  if (nib) {
    int b = idx / NVOX;
    int4 L = *(const int4*)(lab + idx);        // lab may alias out: read first
    const unsigned int* cb = counts + (size_t)b * NVOX;
    rr.x = (L.x > 0 && cb[L.x - 1] >= 100u) ? 1.f : 0.f;
    rr.y = (L.y > 0 && cb[L.y - 1] >= 100u) ? 1.f : 0.f;
    rr.z = (L.z > 0 && cb[L.z - 1] >= 100u) ? 1.f : 0.f;
    rr.w = (L.w > 0 && cb[L.w - 1] >= 100u) ? 1.f : 0.f;
  }
  *(float4*)(out + idx) = rr;
}

// ---- host-side: emulate numpy f32 pairwise sum exactly ----
static float np_sum_f32(const float* a, int n) {
  if (n < 8) { float res = 0.f; for (int i = 0; i < n; i++) res += a[i]; return res; }
  float r[8]; for (int j = 0; j < 8; j++) r[j] = a[j];
  int i = 8;
  for (; i < n - (n % 8); i += 8) for (int j = 0; j < 8; j++) r[j] += a[i + j];
  float res = ((r[0] + r[1]) + (r[2] + r[3])) + ((r[4] + r[5]) + (r[6] + r[7]));
  for (; i < n; i++) res += a[i];
  return res;
}

extern "C" void kernel_launch(void* const* d_in, const int* in_sizes, int n_in,
                              void* d_out, int out_size, void* d_ws, size_t ws_size,
                              hipStream_t stream) {
  const float* v = (const float*)d_in[0];
  float* out = (float*)d_out;
  char* base = (char*)d_ws;
  const size_t SZBUF = (size_t)NTOT * 4;     // 56.6 MB
  const size_t SZW   = (size_t)W3 * 8;       // 1.77 MB

  float* A  = (float*)base;
  float* Cf = (float*)(base + SZBUF);
  unsigned int* mx = (unsigned int*)(base + 2 * SZBUF);
  float* bmax = (float*)(base + 2 * SZBUF + 256);
  float* Bf = (float*)d_out;

  u64* lowW    = (u64*)base;
  u64* mWA     = (u64*)(base + SZW);
  u64* mWB     = (u64*)(base + 2 * SZW);
  u64* closedW = (u64*)(base + 3 * SZW);
  u64* chgWA   = (u64*)(base + 4 * SZW);
  u64* chgWB   = (u64*)(base + 5 * SZW);
  u64* sumA    = (u64*)(base + 6 * SZW);
  u64* sumB    = sumA + NSUM;
  int* chgH = (int*)(sumB + NSUM);         // 32
  int* chgC = chgH + 32;                   // 256
  int* hF0  = chgC + 256;                  // 288
  int* hF1  = hF0 + NHT;                   // 288
  size_t ctrlBytes = (char*)(hF1 + NHT) - (char*)chgH;

  int* labA = (int*)Bf;                    // S_0 / even states; final labels here
  int* labB = (int*)Cf;
  unsigned int* counts = (unsigned int*)Cf;   // labB dead after CC

  dim3 g(NBLK), gw(WBLK), gq(NQB), blk(256);

  const double sigmas[2] = {1.0, 2.0};
  for (int si = 0; si < 2; ++si) {
    double sigma = sigmas[si];
    int r = (int)(3.0 * sigma + 0.5);
    int n = 2 * r + 1;
    float a[13], k[13];
    for (int i = 0; i < n; i++) {
      float xx = (float)(i - r);
      float t  = xx * xx;
      float arg = -(t) / (float)(2.0 * sigma * sigma);
      a[i] = (float)std::exp((double)arg);
    }
    float ssum = np_sum_f32(a, n);
    for (int i = 0; i < n; i++) k[i] = a[i] / ssum;

    Taps13 T = {};
    for (int i = 0; i < n; i++) T.k[i] = k[i];
    float scale = (float)(sigma * sigma);
    float* starget = (si == 0) ? Cf : Bf;

    if (r == 3) {
      conv1d_k<0, 3><<<g, blk, 0, stream>>>(v,  A,  T);
      conv1d_k<1, 3><<<g, blk, 0, stream>>>(A,  Bf, T);
      conv1d_k<2, 3><<<g, blk, 0, stream>>>(Bf, A,  T);
    } else {
      conv1d_k<0, 6><<<g, blk, 0, stream>>>(v,  A,  T);
      conv1d_k<1, 6><<<g, blk, 0, stream>>>(A,  Bf, T);
      conv1d_k<2, 6><<<g, blk, 0, stream>>>(Bf, A,  T);
    }
    surf_k<<<g, blk, 0, stream>>>(A, starget, bmax, scale);
    reduce_max_k<<<dim3(2), blk, 0, stream>>>(bmax, mx + 2 * si);
  }

  // A's f32 data dead from here; packed masks / flags reuse its footprint.
  hipMemsetAsync(chgH, 0, ctrlBytes, stream);
  mask_init_pack_k<<<g, blk, 0, stream>>>(v, Cf, Bf, mx, lowW, mWA);

  // hysteresis: 32 x (8 exact steps) == F^256, tile-skip + global early-exit
  for (int it = 0; it < 32; ++it) {
    const u64* s = (it & 1) ? mWB : mWA;
    u64*       d = (it & 1) ? mWA : mWB;
    const int* fp = (it & 1) ? hF0 : hF1;
    int*       fc = (it & 1) ? hF1 : hF0;
    hyst8_k<<<dim3(12, 12, 2), blk, 0, stream>>>(s, d, lowW, fp, fc, chgH, it);
  }
  // state in mWA (or both equal if converged early)

  close_z_k<<<gw, blk, 0, stream>>>(mWA, closedW);

  // CC step 1 fused with label init: S_0 -> labA, S_1 -> labB, chg -> chgWB/sumB
  cc_init_fused_k<<<gw, blk, 0, stream>>>(closedW, labA, labB, chgWB, sumB, chgC);

  // CC steps 2..256: 255 x cc_word (proven voxel-granular skip + summary)
  for (int it = 1; it < 256; ++it) {
    const int* s = (it & 1) ? labB : labA;
    int*       d = (it & 1) ? labA : labB;
    const u64* cp = (it & 1) ? chgWB : chgWA;
    u64*       cc = (it & 1) ? chgWA : chgWB;
    const u64* sp = (it & 1) ? sumB : sumA;
    u64*       sc = (it & 1) ? sumA : sumB;
    cc_word_k<<<gw, blk, 0, stream>>>(s, d, cp, cc, sp, sc, closedW, chgC, it);
  }
  // final labels in labA (= d_out region; skipped voxels equal in both buffers)

  hipMemsetAsync(counts, 0, SZBUF, stream);
  count_k<<<gq, blk, 0, stream>>>(labA, closedW, counts);
  final_k<<<gq, blk, 0, stream>>>(labA, closedW, counts, out);
}